// Round 1
// baseline (20.054 us; speedup 1.0000x reference)
//
#include <hip/hip_runtime.h>

// Problem: B=25, N=16, S=5, C=S*S=25.
// out[k] = (1/B) * sum_b dis_loss[b,k]  +  (1/(B*C)) * sum_{b,c} p_loss[b,c]
// (derived from the (B,C)+(B,C,1) broadcast in the reference, valid since B==C)

#define MAXB 64
#define MAXN 32
#define MAXC 32

__global__ __launch_bounds__(64) void loss_26405458936156_kernel(
    const float* __restrict__ pred,   // (B, 3*C) row-major, [conf, x, y] per cell
    const int*   __restrict__ truth,  // (B, N, 2) int32
    const int*   __restrict__ Sp,     // scalar S
    float*       __restrict__ out,    // (C,)
    int B, int N)
{
    const int   S    = Sp[0];
    const int   C    = S * S;
    const float cell = 80.0f / (float)S;     // 16.0 for S=5 (exact)
    const float inv  = (float)S / 80.0f;     // 0.0625 (exact)

    __shared__ float sh_dis[MAXB][MAXN];
    __shared__ float sh_p[MAXB];

    const int t = threadIdx.x;
    float psum = 0.0f;

    if (t < B) {
        const float* pb = pred  + t * 3 * C;
        const int*   tb = truth + t * 2 * N;

        float txa[MAXN], tya[MAXN];
        int   lab[MAXN];
        int   counts[MAXC];
        for (int c = 0; c < C; ++c) counts[c] = 0;

        for (int n = 0; n < N; ++n) {
            float t0 = (float)tb[2*n]   + 14.0f;   // in [14, 80)
            float t1 = (float)tb[2*n+1] + 14.0f;
            float tx = fmodf(t0, cell) * inv;
            float ty = fmodf(t1, cell) * inv;
            int   lb = (int)(floorf(t0 / cell) * (float)S + floorf(t1 / cell));
            txa[n] = tx; tya[n] = ty; lab[n] = lb;
            counts[lb]++;
        }

        const float txl = txa[N-1] * 16.0f;
        const float tyl = tya[N-1] * 16.0f;

        // p_loss over all C cells of this batch
        for (int c = 0; c < C; ++c) {
            float conf = pb[3*c+0];
            float cx   = pb[3*c+1];
            float cy   = pb[3*c+2];
            float dx   = fabsf(cx * 16.0f - txl);
            float dy   = fabsf(cy * 16.0f - tyl);
            float iou  = fmaxf(28.0f - 2.0f*dx, 0.0f) * fmaxf(28.0f - 2.0f*dy, 0.0f)
                       / ((28.0f + dx) * (28.0f + dy));
            float p;
            if (counts[c] == N) { float e = conf - iou; p = e * e; }
            else                { p = 0.5f * conf * conf; }
            psum += p;
        }

        // dis_loss: gather coords at label[n]
        for (int n = 0; n < N; ++n) {
            float px = pb[3*lab[n]+1];
            float py = pb[3*lab[n]+2];
            float ex = px - txa[n];
            float ey = py - tya[n];
            sh_dis[t][n] = 5.0f * (ex*ex + ey*ey);
        }
    }
    if (t < MAXB) sh_p[t] = (t < B) ? psum : 0.0f;
    __syncthreads();

    // thread k (k < C) writes out[k]
    if (t < C) {
        float P = 0.0f;
        for (int b = 0; b < B; ++b) P += sh_p[b];
        P *= 1.0f / (float)(B * C);

        float acc = 0.0f;
        if (t < N) {
            for (int b = 0; b < B; ++b) acc += sh_dis[b][t];
            acc *= 1.0f / (float)B;
        }
        out[t] = acc + P;
    }
}

extern "C" void kernel_launch(void* const* d_in, const int* in_sizes, int n_in,
                              void* d_out, int out_size, void* d_ws, size_t ws_size,
                              hipStream_t stream) {
    const float* pred  = (const float*)d_in[0];
    const int*   truth = (const int*)d_in[1];
    const int*   Sp    = (const int*)d_in[2];
    float*       out   = (float*)d_out;

    // pred is (B, 3*S*S) with S=5 fixed by the problem -> 75 floats/row
    const int B = in_sizes[0] / 75;
    const int N = in_sizes[1] / (2 * B);

    loss_26405458936156_kernel<<<1, 64, 0, stream>>>(pred, truth, Sp, out, B, N);
}

// Round 2
// 9.837 us; speedup vs baseline: 2.0387x; 2.0387x over previous
//
#include <hip/hip_runtime.h>

// B=25, N=16, S=5, C=25.
// out[k] = (1/B)*sum_b dis_loss[b,k] + (1/(B*C))*sum_{b,c} p_loss[b,c]
//   (the reference's (B,C)+(B,C,1) broadcast followed by two means, B==C)
// all_match[b,c] == (counts[b,c]==N) == (every point of batch b has label c).

#define MAXB 32
#define MAXN 16
#define MAXPRED (32*80)

__global__ __launch_bounds__(256) void loss_26405458936156_kernel(
    const float* __restrict__ pred,   // (B, 3*C)
    const int*   __restrict__ truth,  // (B, N, 2) int32
    const int*   __restrict__ Sp,     // scalar S
    float*       __restrict__ out,    // (C,)
    int B, int N)
{
    const int t = threadIdx.x;

    __shared__ float s_pred[MAXPRED];
    __shared__ float s_tx[MAXB][MAXN], s_ty[MAXB][MAXN];
    __shared__ int   s_lab[MAXB][MAXN];
    __shared__ int   s_amc[MAXB];            // uniform label, or -1
    __shared__ float s_txl[MAXB], s_tyl[MAXB];
    __shared__ float s_dis[MAXB][MAXN];
    __shared__ float s_wsum[4];

    const int   S     = Sp[0];
    const int   C     = S * S;
    const float cell  = 80.0f / (float)S;    // 16.0 (exact)
    const float cellr = (float)S / 80.0f;    // 0.0625 (exact)

    // Prefetch pred into LDS — overlaps with the truth-dependent phase A.
    const int PN = B * 3 * C;
    for (int i = t; i < PN; i += 256) s_pred[i] = pred[i];

    // Phase A1: per-(b,n) transform of truth.
    for (int i = t; i < B * N; i += 256) {
        int b = i / N, n = i - b * N;
        float t0 = (float)truth[2*i]   + 14.0f;   // in [14, 80)
        float t1 = (float)truth[2*i+1] + 14.0f;
        float fx = floorf(t0 * cellr);
        float fy = floorf(t1 * cellr);
        float tx = (t0 - fx * cell) * cellr;      // == fmod(t0,cell)/cell, exact here
        float ty = (t1 - fy * cell) * cellr;
        s_tx[b][n]  = tx;
        s_ty[b][n]  = ty;
        s_lab[b][n] = (int)(fx * (float)S + fy);
    }
    __syncthreads();

    // Phase A2: per-batch uniform-label check + last-point coords.
    if (t < B) {
        int l0 = s_lab[t][0], all = 1;
        for (int n = 1; n < N; ++n) all &= (s_lab[t][n] == l0);
        s_amc[t] = all ? l0 : -1;
        s_txl[t] = s_tx[t][N-1] * 16.0f;
        s_tyl[t] = s_ty[t][N-1] * 16.0f;
    }
    __syncthreads();

    // Phase B: p_loss over (b,c), thread-partial sums.
    float psum = 0.0f;
    for (int i = t; i < B * C; i += 256) {
        int b = i / C, c = i - b * C;
        const float* pb = &s_pred[b * 3 * C + 3 * c];
        float conf = pb[0], cx = pb[1], cy = pb[2];
        float dx = fabsf(cx * 16.0f - s_txl[b]);
        float dy = fabsf(cy * 16.0f - s_tyl[b]);
        float iou = fmaxf(28.0f - 2.0f*dx, 0.0f) * fmaxf(28.0f - 2.0f*dy, 0.0f)
                  / ((28.0f + dx) * (28.0f + dy));
        float e = conf - iou;
        psum += (s_amc[b] == c) ? e * e : 0.5f * conf * conf;
    }

    // Phase C: dis_loss over (b,n).
    for (int i = t; i < B * N; i += 256) {
        int b = i / N, n = i - b * N;
        int lb = s_lab[b][n];
        float px = s_pred[b * 3 * C + 3 * lb + 1];
        float py = s_pred[b * 3 * C + 3 * lb + 2];
        float ex = px - s_tx[b][n], ey = py - s_ty[b][n];
        s_dis[b][n] = 5.0f * (ex * ex + ey * ey);
    }

    // Wave-reduce psum (wave = 64), one partial per wave.
    for (int o = 32; o > 0; o >>= 1) psum += __shfl_down(psum, o);
    if ((t & 63) == 0) s_wsum[t >> 6] = psum;
    __syncthreads();

    // Output: thread k < C writes out[k].
    if (t < C) {
        float P = (s_wsum[0] + s_wsum[1] + s_wsum[2] + s_wsum[3])
                  * (1.0f / (float)(B * C));
        float acc = 0.0f;
        if (t < N) {
            for (int b = 0; b < B; ++b) acc += s_dis[b][t];
            acc *= 1.0f / (float)B;
        }
        out[t] = acc + P;
    }
}

extern "C" void kernel_launch(void* const* d_in, const int* in_sizes, int n_in,
                              void* d_out, int out_size, void* d_ws, size_t ws_size,
                              hipStream_t stream) {
    const float* pred  = (const float*)d_in[0];
    const int*   truth = (const int*)d_in[1];
    const int*   Sp    = (const int*)d_in[2];
    float*       out   = (float*)d_out;

    // pred is (B, 3*S*S) with S=5 for this problem -> 75 floats/row
    const int B = in_sizes[0] / 75;
    const int N = in_sizes[1] / (2 * B);

    loss_26405458936156_kernel<<<1, 256, 0, stream>>>(pred, truth, Sp, out, B, N);
}

// Round 3
// 9.372 us; speedup vs baseline: 2.1397x; 1.0495x over previous
//
#include <hip/hip_runtime.h>

// B=25, N=16, S=5, C=25 (S,N,C hardcoded — fixed by the problem; B runtime).
// out[k] = (1/B)*sum_b dis_loss[b,k] + (1/(B*C))*sum_{b,c} p_loss[b,c]
//   (the reference's (B,C)+(B,C,1) broadcast followed by two means, B==C)
// all_match[b,c] == (counts[b,c]==N) == (every point of batch b has label c).
//
// Latency-floor design: ONE __syncthreads total.
//   cycle 0:  issue pred->LDS staging (also warms L1 for the gather) + truth loads
//   phase A+C fused per (b,n): transform truth (exact fp32: inputs integer-valued,
//             cell=16=2^4), write labels, gather pred from L1, write dis to LDS
//   barrier
//   wave 0:   all_match (pad-17 LDS rows, conflict-free), 625-item p_loss loop
//             with __shfl operand broadcast, 64-lane shuffle reduce, store.

#define NT 256

__global__ __launch_bounds__(NT) void loss_26405458936156_kernel(
    const float* __restrict__ pred,   // (B, 75)
    const int*   __restrict__ truth,  // (B, 16, 2) int32
    float*       __restrict__ out,    // (25,)
    int B)
{
    const float cell  = 16.0f;     // 80/S, exact
    const float cellr = 0.0625f;   // S/80, exact (2^-4)

    __shared__ float s_pred[64 * 75];
    __shared__ int   s_lab[64][17];   // pad 17: all-match reads conflict-free
    __shared__ float s_dis[64][17];
    __shared__ float s_txl[64], s_tyl[64];

    const int t = threadIdx.x;

    // Stage pred -> LDS (issued first; overlaps the truth-dependent phase,
    // and pulls every pred line through L1 for the gather below).
    const int PN = B * 75;
    for (int i = t; i < PN; i += NT) s_pred[i] = pred[i];

    // Phase A+C fused: per-(b,n) truth transform + dis_loss gather.
    const int2* tr = (const int2*)truth;   // (x,y) pairs, 8B aligned
    for (int i = t; i < B * 16; i += NT) {
        int b = i >> 4, n = i & 15;
        int2 tv = tr[i];
        float t0 = (float)tv.x + 14.0f;          // integer-valued, [14,80)
        float t1 = (float)tv.y + 14.0f;
        float fx = floorf(t0 * cellr);           // exact
        float fy = floorf(t1 * cellr);
        float tx = (t0 - fx * cell) * cellr;     // == fmod(t0,cell)*S/80, exact
        float ty = (t1 - fy * cell) * cellr;
        int   lb = (int)fx * 5 + (int)fy;
        s_lab[b][n] = lb;
        if (n == 15) { s_txl[b] = tx * 16.0f; s_tyl[b] = ty * 16.0f; }
        // gather own dis_loss term (pred lines L1-resident from staging loads)
        float px = pred[b * 75 + 3 * lb + 1];
        float py = pred[b * 75 + 3 * lb + 2];
        float ex = px - tx, ey = py - ty;
        s_dis[b][n] = 5.0f * (ex * ex + ey * ey);
    }
    __syncthreads();

    // Wave 0 finishes everything — no further barriers.
    if (t < 64) {
        // all_match + last-point coords, one batch per lane
        int   amc = -1;
        float txl = 0.0f, tyl = 0.0f;
        if (t < B) {
            int l0 = s_lab[t][0], all = 1;
            #pragma unroll
            for (int n = 1; n < 16; ++n) all &= (s_lab[t][n] == l0);
            amc = all ? l0 : -1;
            txl = s_txl[t];
            tyl = s_tyl[t];
        }

        // p_loss over all (b,c): operands broadcast via shuffles (no LDS round-trip)
        float psum = 0.0f;
        for (int i = t; i < B * 25; i += 64) {
            int b = i / 25, c = i - b * 25;
            const float* pc = &s_pred[b * 75 + 3 * c];
            float conf = pc[0], cx = pc[1], cy = pc[2];
            int   amcb = __shfl(amc, b);
            float txlb = __shfl(txl, b);
            float tylb = __shfl(tyl, b);
            float dx = fabsf(cx * 16.0f - txlb);
            float dy = fabsf(cy * 16.0f - tylb);
            float iou = fmaxf(28.0f - 2.0f * dx, 0.0f) * fmaxf(28.0f - 2.0f * dy, 0.0f)
                      / ((28.0f + dx) * (28.0f + dy));
            float e = conf - iou;
            psum += (amcb == c) ? e * e : 0.5f * conf * conf;
        }
        // 64-lane butterfly reduce
        #pragma unroll
        for (int o = 32; o; o >>= 1) psum += __shfl_xor(psum, o);

        if (t < 25) {
            float P = psum * (1.0f / (float)(B * 25));
            float acc = 0.0f;
            if (t < 16) {
                for (int b = 0; b < B; ++b) acc += s_dis[b][t];
                acc *= 1.0f / (float)B;
            }
            out[t] = acc + P;
        }
    }
}

extern "C" void kernel_launch(void* const* d_in, const int* in_sizes, int n_in,
                              void* d_out, int out_size, void* d_ws, size_t ws_size,
                              hipStream_t stream) {
    const float* pred  = (const float*)d_in[0];
    const int*   truth = (const int*)d_in[1];
    float*       out   = (float*)d_out;

    const int B = in_sizes[0] / 75;   // pred is (B, 3*S*S), S=5

    loss_26405458936156_kernel<<<1, NT, 0, stream>>>(pred, truth, out, B);
}